// Round 1
// baseline (545.719 us; speedup 1.0000x reference)
//
#include <hip/hip_runtime.h>
#include <stdint.h>

typedef unsigned short u16;
typedef unsigned int   u32;
typedef __attribute__((ext_vector_type(4))) float f32x4;
typedef __attribute__((ext_vector_type(8))) short bf16x8;

#define DIM    1024
#define NROWS  8192
#define NLAYER 10

// ---------- bf16 split helpers ----------
__device__ __forceinline__ u16 f2bf(float x) {
    u32 u = __float_as_uint(x);
    u32 r = u + 0x7FFFu + ((u >> 16) & 1u);   // RNE
    return (u16)(r >> 16);
}
__device__ __forceinline__ float bf2f(u16 h) { return __uint_as_float(((u32)h) << 16); }

__device__ __forceinline__ void gl_lds16(const void* g, void* l) {
    __builtin_amdgcn_global_load_lds((const __attribute__((address_space(1))) u32*)g,
                                     (__attribute__((address_space(3))) u32*)l, 16, 0, 0);
}

// ---------- conversion kernels: f32 -> (bf16 hi, bf16 lo) planes ----------
// weights: W0 [1024*1024] then Wh [9*1024*1024] -> Whi/Wlo [10*1024*1024]
__global__ __launch_bounds__(256) void conv_weights(const float* __restrict__ W0,
                                                    const float* __restrict__ Wh,
                                                    u16* __restrict__ Whi,
                                                    u16* __restrict__ Wlo) {
    int i = (blockIdx.x * 256 + threadIdx.x) * 4;   // covers 10*1024*1024 exactly
    const float* src = (i < 1048576) ? (W0 + i) : (Wh + (i - 1048576));
    float4 w = *(const float4*)src;
    ushort4 hi, lo;
    hi.x = f2bf(w.x); lo.x = f2bf(w.x - bf2f(hi.x));
    hi.y = f2bf(w.y); lo.y = f2bf(w.y - bf2f(hi.y));
    hi.z = f2bf(w.z); lo.z = f2bf(w.z - bf2f(hi.z));
    hi.w = f2bf(w.w); lo.w = f2bf(w.w - bf2f(hi.w));
    *(ushort4*)(Whi + i) = hi;
    *(ushort4*)(Wlo + i) = lo;
}

__global__ __launch_bounds__(256) void conv_x(const float* __restrict__ x,
                                              u16* __restrict__ Ahi,
                                              u16* __restrict__ Alo) {
    int i = (blockIdx.x * 256 + threadIdx.x) * 4;   // covers 8192*1024 exactly
    float4 w = *(const float4*)(x + i);
    ushort4 hi, lo;
    hi.x = f2bf(w.x); lo.x = f2bf(w.x - bf2f(hi.x));
    hi.y = f2bf(w.y); lo.y = f2bf(w.y - bf2f(hi.y));
    hi.z = f2bf(w.z); lo.z = f2bf(w.z - bf2f(hi.z));
    hi.w = f2bf(w.w); lo.w = f2bf(w.w - bf2f(hi.w));
    *(ushort4*)(Ahi + i) = hi;
    *(ushort4*)(Alo + i) = lo;
}

// ---------- fused layer: C = A (M=8192 x K=1024) * W^T (N=1024 x K) + bias, sigmoid, re-split ----------
// Tiles: BM=256, BN=128, BK=64. 512 threads = 8 waves (4M x 2N), per-wave 64x64 out.
// Split-bf16: C = Ah*Bh + Ah*Bl + Al*Bh (3 MFMAs per fragment pair).
#define BM 256
#define BN 128
#define BK 64
// LDS byte offsets (single combined array, linear layout for global_load_lds):
#define A_HI_B 0          // [256][64] bf16 = 32 KB
#define A_LO_B 32768
#define B_HI_B 65536      // [128][64] bf16 = 16 KB
#define B_LO_B 81920
// total 96 KB

__global__ __launch_bounds__(512, 2) void layer_gemm(
        const u16* __restrict__ Ahi, const u16* __restrict__ Alo,
        const u16* __restrict__ Bhi_g, const u16* __restrict__ Blo_g,
        const float* __restrict__ bias,
        u16* __restrict__ Ohi, u16* __restrict__ Olo) {
    __shared__ u16 lds[49152];   // 96 KB

    // XCD-aware bijective swizzle: 256 blocks, 8 XCDs, 32/XCD
    int bid = blockIdx.x;
    int swz = (bid & 7) * 32 + (bid >> 3);
    int bn = swz & 7;    // 0..7   (N blocks) -- consecutive swz share bm => A panel L2-hot
    int bm = swz >> 3;   // 0..31  (M blocks)

    const int tid  = threadIdx.x;
    const int lane = tid & 63;
    const int wid  = tid >> 6;   // 0..7
    const int wr   = wid >> 1;   // 0..3  M-row of wave
    const int wc   = wid & 1;    // 0..1  N-col of wave

    // ---- staging setup: 96 chunks of 1KB (8 rows x 128B), 12 per wave ----
    // pre-swizzled global source so linear global_load_lds lands XOR-swizzled:
    // logical (row r, colbyte cb) lives at LDS r*128 + (cb ^ ((r&7)<<4))
    const int swcol = (((lane & 7) ^ ((lane >> 3) & 7)) << 4);
    const char* gsrc[12];
    u32 ldst[12];
    #pragma unroll
    for (int j = 0; j < 12; ++j) {
        int c = wid * 12 + j;
        if (c < 64) {                       // A planes
            int p  = c >> 5;                // 0=hi 1=lo
            int cc = c & 31;
            int grow = bm * 256 + cc * 8 + (lane >> 3);
            gsrc[j] = (const char*)(p ? Alo : Ahi) + (size_t)grow * 2048 + swcol;
            ldst[j] = (p ? A_LO_B : A_HI_B) + cc * 1024;
        } else {                            // B planes
            int c2 = c - 64;
            int p  = c2 >> 4;
            int cc = c2 & 15;
            int grow = bn * 128 + cc * 8 + (lane >> 3);
            gsrc[j] = (const char*)(p ? Blo_g : Bhi_g) + (size_t)grow * 2048 + swcol;
            ldst[j] = (p ? B_LO_B : B_HI_B) + cc * 1024;
        }
    }

    f32x4 acc[4][4];
    #pragma unroll
    for (int mf = 0; mf < 4; ++mf)
        #pragma unroll
        for (int nf = 0; nf < 4; ++nf)
            acc[mf][nf] = (f32x4){0.f, 0.f, 0.f, 0.f};

    for (int kt = 0; kt < DIM / BK; ++kt) {
        // stage (async, linear LDS dest; source pre-swizzled)
        #pragma unroll
        for (int j = 0; j < 12; ++j)
            gl_lds16(gsrc[j] + (size_t)kt * 128, (char*)lds + ldst[j]);
        __syncthreads();   // drains vmcnt -> LDS tile complete

        #pragma unroll
        for (int ks = 0; ks < 2; ++ks) {
            bf16x8 a_h[4], a_l[4], b_h[4], b_l[4];
            const int cb = ks * 64 + ((lane >> 4) << 4);  // 16B-aligned col byte
            #pragma unroll
            for (int mf = 0; mf < 4; ++mf) {
                int r = wr * 64 + mf * 16 + (lane & 15);
                int byt = r * 128 + (cb ^ ((r & 7) << 4));
                a_h[mf] = *(const bf16x8*)((const char*)lds + A_HI_B + byt);
                a_l[mf] = *(const bf16x8*)((const char*)lds + A_LO_B + byt);
            }
            #pragma unroll
            for (int nf = 0; nf < 4; ++nf) {
                int r = wc * 64 + nf * 16 + (lane & 15);
                int byt = r * 128 + (cb ^ ((r & 7) << 4));
                b_h[nf] = *(const bf16x8*)((const char*)lds + B_HI_B + byt);
                b_l[nf] = *(const bf16x8*)((const char*)lds + B_LO_B + byt);
            }
            #pragma unroll
            for (int mf = 0; mf < 4; ++mf)
                #pragma unroll
                for (int nf = 0; nf < 4; ++nf) {
                    acc[mf][nf] = __builtin_amdgcn_mfma_f32_16x16x32_bf16(a_h[mf], b_h[nf], acc[mf][nf], 0, 0, 0);
                    acc[mf][nf] = __builtin_amdgcn_mfma_f32_16x16x32_bf16(a_h[mf], b_l[nf], acc[mf][nf], 0, 0, 0);
                    acc[mf][nf] = __builtin_amdgcn_mfma_f32_16x16x32_bf16(a_l[mf], b_h[nf], acc[mf][nf], 0, 0, 0);
                }
        }
        __syncthreads();   // protect LDS before next stage
    }

    // ---- epilogue: bias + sigmoid + split-store (C layout: col=lane&15, row=(lane>>4)*4+j) ----
    float bv[4];
    #pragma unroll
    for (int nf = 0; nf < 4; ++nf)
        bv[nf] = bias[bn * 128 + wc * 64 + nf * 16 + (lane & 15)];

    #pragma unroll
    for (int mf = 0; mf < 4; ++mf) {
        #pragma unroll
        for (int nf = 0; nf < 4; ++nf) {
            int gn = bn * 128 + wc * 64 + nf * 16 + (lane & 15);
            #pragma unroll
            for (int j = 0; j < 4; ++j) {
                int gm = bm * 256 + wr * 64 + mf * 16 + ((lane >> 4) << 2) + j;
                float z = acc[mf][nf][j] + bv[nf];
                float h = 1.0f / (1.0f + __expf(-z));
                u16 hi = f2bf(h);
                u16 lo = f2bf(h - bf2f(hi));
                size_t o = (size_t)gm * DIM + gn;
                Ohi[o] = hi;
                Olo[o] = lo;
            }
        }
    }
}

// ---------- output GEMV: out[m] = sum_k (hi+lo)[m][k] * Wout[k] + bout ----------
__global__ __launch_bounds__(256) void out_gemv(const u16* __restrict__ Ahi,
                                                const u16* __restrict__ Alo,
                                                const float* __restrict__ Wout,
                                                const float* __restrict__ bout,
                                                float* __restrict__ out) {
    int wid  = threadIdx.x >> 6;
    int lane = threadIdx.x & 63;
    int row  = blockIdx.x * 4 + wid;
    const u16* ph = Ahi + (size_t)row * DIM + lane * 16;
    const u16* pl = Alo + (size_t)row * DIM + lane * 16;
    const float* pw = Wout + lane * 16;
    float s = 0.f;
    #pragma unroll
    for (int i = 0; i < 4; ++i) {
        ushort4 h4 = *(const ushort4*)(ph + i * 4);
        ushort4 l4 = *(const ushort4*)(pl + i * 4);
        float4  w4 = *(const float4*)(pw + i * 4);
        s += (bf2f(h4.x) + bf2f(l4.x)) * w4.x;
        s += (bf2f(h4.y) + bf2f(l4.y)) * w4.y;
        s += (bf2f(h4.z) + bf2f(l4.z)) * w4.z;
        s += (bf2f(h4.w) + bf2f(l4.w)) * w4.w;
    }
    #pragma unroll
    for (int off = 32; off > 0; off >>= 1)
        s += __shfl_down(s, off);
    if (lane == 0) out[row] = s + bout[0];
}

// ---------- launcher ----------
extern "C" void kernel_launch(void* const* d_in, const int* in_sizes, int n_in,
                              void* d_out, int out_size, void* d_ws, size_t ws_size,
                              hipStream_t stream) {
    const float* x    = (const float*)d_in[0];
    const float* W0   = (const float*)d_in[1];
    const float* b0   = (const float*)d_in[2];
    const float* Wh   = (const float*)d_in[3];
    const float* bh   = (const float*)d_in[4];
    const float* Wout = (const float*)d_in[5];
    const float* bout = (const float*)d_in[6];
    float* out = (float*)d_out;

    u16* ws  = (u16*)d_ws;
    u16* Whi = ws;                                 // 10*1024*1024
    u16* Wlo = Whi + (size_t)NLAYER * DIM * DIM;
    u16* A0h = Wlo + (size_t)NLAYER * DIM * DIM;   // 8192*1024 each
    u16* A0l = A0h + (size_t)NROWS * DIM;
    u16* A1h = A0l + (size_t)NROWS * DIM;
    u16* A1l = A1h + (size_t)NROWS * DIM;

    conv_weights<<<NLAYER * DIM * DIM / 1024, 256, 0, stream>>>(W0, Wh, Whi, Wlo);
    conv_x<<<NROWS * DIM / 1024, 256, 0, stream>>>(x, A0h, A0l);

    const u16 *ih = A0h, *il = A0l;
    u16 *oh = A1h, *ol = A1l;
    for (int l = 0; l < NLAYER; ++l) {
        const float* bias = (l == 0) ? b0 : (bh + (size_t)(l - 1) * DIM);
        layer_gemm<<<256, 512, 0, stream>>>(ih, il,
                                            Whi + (size_t)l * DIM * DIM,
                                            Wlo + (size_t)l * DIM * DIM,
                                            bias, oh, ol);
        const u16* th = ih; const u16* tl = il;
        ih = oh; il = ol;
        oh = (u16*)th; ol = (u16*)tl;
    }

    out_gemv<<<NROWS / 4, 256, 0, stream>>>(ih, il, Wout, bout, out);
}

// Round 2
// 256.751 us; speedup vs baseline: 2.1255x; 2.1255x over previous
//
#include <hip/hip_runtime.h>
#include <stdint.h>

typedef unsigned short u16;
typedef unsigned int   u32;
typedef _Float16 f16;
typedef __attribute__((ext_vector_type(4))) float    f32x4;
typedef __attribute__((ext_vector_type(8))) _Float16 f16x8;
typedef __attribute__((ext_vector_type(4))) _Float16 f16x4;

#define DIM    1024
#define NROWS  8192
#define NLAYER 10

__device__ __forceinline__ void gl_lds16(const void* g, void* l) {
    __builtin_amdgcn_global_load_lds((const __attribute__((address_space(1))) u32*)g,
                                     (__attribute__((address_space(3))) u32*)l, 16, 0, 0);
}

// ---------- conversion: f32 -> f16 plane ----------
__global__ __launch_bounds__(256) void conv_weights(const float* __restrict__ W0,
                                                    const float* __restrict__ Wh,
                                                    f16* __restrict__ Wf) {
    int i = (blockIdx.x * 256 + threadIdx.x) * 4;   // covers 10*1024*1024
    const float* src = (i < 1048576) ? (W0 + i) : (Wh + (i - 1048576));
    float4 w = *(const float4*)src;
    f16x4 o;
    o.x = (f16)w.x; o.y = (f16)w.y; o.z = (f16)w.z; o.w = (f16)w.w;
    *(f16x4*)(Wf + i) = o;
}

__global__ __launch_bounds__(256) void conv_x(const float* __restrict__ x,
                                              f16* __restrict__ Af) {
    int i = (blockIdx.x * 256 + threadIdx.x) * 4;   // covers 8192*1024
    float4 w = *(const float4*)(x + i);
    f16x4 o;
    o.x = (f16)w.x; o.y = (f16)w.y; o.z = (f16)w.z; o.w = (f16)w.w;
    *(f16x4*)(Af + i) = o;
}

// ---------- fused layer: C = A(8192xK) * W^T + bias, sigmoid -> f16 ----------
// BM=256 BN=128 BK=64, 512 threads = 8 waves (4M x 2N), 64x64/wave, f16 MFMA.
// Double-buffered LDS: 2 x (A 32KB + B 16KB) = 96KB. 2-phase pipeline:
// stage(next) -> compute(cur) -> __syncthreads (vmcnt drain covered by compute).
#define ABUF_B 0        // [256][64] f16 = 32 KB
#define BBUF_B 32768    // [128][64] f16 = 16 KB
#define BUFSZ  49152

__global__ __launch_bounds__(512, 2) void layer_gemm(
        const f16* __restrict__ A,
        const f16* __restrict__ Bg,
        const float* __restrict__ bias,
        f16* __restrict__ O) {
    __shared__ char lds[2 * BUFSZ];   // 96 KB

    // XCD-aware bijective swizzle: 256 blocks, 8 XCDs, 32/XCD
    int bid = blockIdx.x;
    int swz = (bid & 7) * 32 + (bid >> 3);
    int bn = swz & 7;    // 0..7
    int bm = swz >> 3;   // 0..31

    const int tid  = threadIdx.x;
    const int lane = tid & 63;
    const int wid  = tid >> 6;
    const int wr   = wid >> 1;   // 0..3
    const int wc   = wid & 1;    // 0..1

    // ---- staging: 48 chunks of 1KB (8 rows x 128B) per K-tile, 6 per wave ----
    // pre-swizzled global source; logical (row r, colbyte cb) at LDS r*128 + (cb ^ ((r&7)<<4))
    const int swcol = (((lane & 7) ^ ((lane >> 3) & 7)) << 4);
    const char* gsrc[6];
    u32 ldst[6];
    #pragma unroll
    for (int j = 0; j < 6; ++j) {
        int c = wid * 6 + j;
        if (c < 32) {                       // A chunks
            int grow = bm * 256 + c * 8 + (lane >> 3);
            gsrc[j] = (const char*)A + (size_t)grow * 2048 + swcol;
            ldst[j] = ABUF_B + c * 1024;
        } else {                            // B chunks
            int c2 = c - 32;
            int grow = bn * 128 + c2 * 8 + (lane >> 3);
            gsrc[j] = (const char*)Bg + (size_t)grow * 2048 + swcol;
            ldst[j] = BBUF_B + c2 * 1024;
        }
    }

    f32x4 acc[4][4];
    #pragma unroll
    for (int mf = 0; mf < 4; ++mf)
        #pragma unroll
        for (int nf = 0; nf < 4; ++nf)
            acc[mf][nf] = (f32x4){0.f, 0.f, 0.f, 0.f};

    // prologue: stage kt=0 into buffer 0
    #pragma unroll
    for (int j = 0; j < 6; ++j)
        gl_lds16(gsrc[j], (char*)lds + ldst[j]);
    __syncthreads();

    for (int kt = 0; kt < DIM / 64; ++kt) {
        const u32 cb_base = (kt & 1) * BUFSZ;
        // stage next K-tile into the other buffer (lands during compute below)
        if (kt < DIM / 64 - 1) {
            const u32 nb = ((kt + 1) & 1) * BUFSZ;
            #pragma unroll
            for (int j = 0; j < 6; ++j)
                gl_lds16(gsrc[j] + (size_t)(kt + 1) * 128, (char*)lds + nb + ldst[j]);
        }

        #pragma unroll
        for (int ks = 0; ks < 2; ++ks) {
            f16x8 a[4], b[4];
            const int cb = ks * 64 + ((lane >> 4) << 4);
            #pragma unroll
            for (int mf = 0; mf < 4; ++mf) {
                int r = wr * 64 + mf * 16 + (lane & 15);
                int byt = r * 128 + (cb ^ ((r & 7) << 4));
                a[mf] = *(const f16x8*)((const char*)lds + cb_base + ABUF_B + byt);
            }
            #pragma unroll
            for (int nf = 0; nf < 4; ++nf) {
                int r = wc * 64 + nf * 16 + (lane & 15);
                int byt = r * 128 + (cb ^ ((r & 7) << 4));
                b[nf] = *(const f16x8*)((const char*)lds + cb_base + BBUF_B + byt);
            }
            __builtin_amdgcn_s_setprio(1);
            #pragma unroll
            for (int mf = 0; mf < 4; ++mf)
                #pragma unroll
                for (int nf = 0; nf < 4; ++nf)
                    acc[mf][nf] = __builtin_amdgcn_mfma_f32_16x16x32_f16(a[mf], b[nf], acc[mf][nf], 0, 0, 0);
            __builtin_amdgcn_s_setprio(0);
        }
        __syncthreads();   // all reads of cur done; next-tile stage drained
    }

    // ---- epilogue: bias + sigmoid -> f16 (C layout: col=lane&15, row=(lane>>4)*4+j) ----
    float bv[4];
    #pragma unroll
    for (int nf = 0; nf < 4; ++nf)
        bv[nf] = bias[bn * 128 + wc * 64 + nf * 16 + (lane & 15)];

    #pragma unroll
    for (int mf = 0; mf < 4; ++mf) {
        #pragma unroll
        for (int nf = 0; nf < 4; ++nf) {
            int gn = bn * 128 + wc * 64 + nf * 16 + (lane & 15);
            #pragma unroll
            for (int j = 0; j < 4; ++j) {
                int gm = bm * 256 + wr * 64 + mf * 16 + ((lane >> 4) << 2) + j;
                float z = acc[mf][nf][j] + bv[nf];
                float h = 1.0f / (1.0f + __expf(-z));
                O[(size_t)gm * DIM + gn] = (f16)h;
            }
        }
    }
}

// ---------- output GEMV ----------
__global__ __launch_bounds__(256) void out_gemv(const f16* __restrict__ A,
                                                const float* __restrict__ Wout,
                                                const float* __restrict__ bout,
                                                float* __restrict__ out) {
    int wid  = threadIdx.x >> 6;
    int lane = threadIdx.x & 63;
    int row  = blockIdx.x * 4 + wid;
    const f16* p = A + (size_t)row * DIM + lane * 16;
    const float* pw = Wout + lane * 16;
    float s = 0.f;
    #pragma unroll
    for (int i = 0; i < 4; ++i) {
        f16x4 h4 = *(const f16x4*)(p + i * 4);
        float4 w4 = *(const float4*)(pw + i * 4);
        s += (float)h4.x * w4.x + (float)h4.y * w4.y + (float)h4.z * w4.z + (float)h4.w * w4.w;
    }
    #pragma unroll
    for (int off = 32; off > 0; off >>= 1)
        s += __shfl_down(s, off);
    if (lane == 0) out[row] = s + bout[0];
}

// ---------- launcher ----------
extern "C" void kernel_launch(void* const* d_in, const int* in_sizes, int n_in,
                              void* d_out, int out_size, void* d_ws, size_t ws_size,
                              hipStream_t stream) {
    const float* x    = (const float*)d_in[0];
    const float* W0   = (const float*)d_in[1];
    const float* b0   = (const float*)d_in[2];
    const float* Wh   = (const float*)d_in[3];
    const float* bh   = (const float*)d_in[4];
    const float* Wout = (const float*)d_in[5];
    const float* bout = (const float*)d_in[6];
    float* out = (float*)d_out;

    f16* ws = (f16*)d_ws;
    f16* Wf = ws;                                  // 10*1024*1024 f16 = 20 MB
    f16* A0 = Wf + (size_t)NLAYER * DIM * DIM;     // 8192*1024 f16 = 16 MB
    f16* A1 = A0 + (size_t)NROWS * DIM;            // 16 MB

    conv_weights<<<NLAYER * DIM * DIM / 1024, 256, 0, stream>>>(W0, Wh, Wf);
    conv_x<<<NROWS * DIM / 1024, 256, 0, stream>>>(x, A0);

    const f16* in = A0;
    f16* o = A1;
    for (int l = 0; l < NLAYER; ++l) {
        const float* bias = (l == 0) ? b0 : (bh + (size_t)(l - 1) * DIM);
        layer_gemm<<<256, 512, 0, stream>>>(in, Wf + (size_t)l * DIM * DIM, bias, o);
        f16* t = (f16*)in; in = o; o = t;
    }

    out_gemv<<<NROWS / 4, 256, 0, stream>>>(in, Wout, bout, out);
}